// Round 1
// baseline (134.488 us; speedup 1.0000x reference)
//
#include <hip/hip_runtime.h>

#define D_NODE 80
#define H 32

// Kernel 1: per-node projection.
// P[n][0:32]  = x[n] @ W1[0:80]            (src projection)
// P[n][32:64] = x[n] @ W1[81:161] + b1 + W1[80]   (dst projection + folded consts)
__global__ __launch_bounds__(256) void proj_kernel(
    const float* __restrict__ X, const float* __restrict__ W1,
    const float* __restrict__ b1, float* __restrict__ P, int N)
{
    __shared__ float sW[161 * 32];
    for (int i = threadIdx.x; i < 161 * 32; i += 256) sW[i] = W1[i];
    __syncthreads();

    int n = blockIdx.x * 256 + threadIdx.x;
    if (n >= N) return;

    float accS[32], accD[32];
#pragma unroll
    for (int j = 0; j < 32; ++j) {
        accS[j] = 0.0f;
        accD[j] = b1[j] + sW[80 * 32 + j];   // folded: b1 + W1 row for constant edge feat
    }

    const float4* x4 = (const float4*)(X + (size_t)n * D_NODE);
#pragma unroll
    for (int k4 = 0; k4 < D_NODE / 4; ++k4) {
        float4 xv = x4[k4];
        float xs[4] = {xv.x, xv.y, xv.z, xv.w};
#pragma unroll
        for (int kk = 0; kk < 4; ++kk) {
            int k = k4 * 4 + kk;
            float xk = xs[kk];
#pragma unroll
            for (int j4 = 0; j4 < 8; ++j4) {
                float4 ws = *(const float4*)&sW[k * 32 + j4 * 4];
                float4 wd = *(const float4*)&sW[(81 + k) * 32 + j4 * 4];
                accS[4 * j4 + 0] += xk * ws.x;
                accS[4 * j4 + 1] += xk * ws.y;
                accS[4 * j4 + 2] += xk * ws.z;
                accS[4 * j4 + 3] += xk * ws.w;
                accD[4 * j4 + 0] += xk * wd.x;
                accD[4 * j4 + 1] += xk * wd.y;
                accD[4 * j4 + 2] += xk * wd.z;
                accD[4 * j4 + 3] += xk * wd.w;
            }
        }
    }

    float4* o4 = (float4*)(P + (size_t)n * 64);
#pragma unroll
    for (int j4 = 0; j4 < 8; ++j4)
        o4[j4] = make_float4(accS[4*j4+0], accS[4*j4+1], accS[4*j4+2], accS[4*j4+3]);
#pragma unroll
    for (int j4 = 0; j4 < 8; ++j4)
        o4[8 + j4] = make_float4(accD[4*j4+0], accD[4*j4+1], accD[4*j4+2], accD[4*j4+3]);
}

// Kernel 2: per-edge MLP tail.
// h1 = relu(P[s][0:32] + P[d][32:64]); h2 = relu(h1@W2 + b2);
// logits = h2@W3 + b3; out = log_softmax(logits)
__global__ __launch_bounds__(256) void edge_kernel(
    const int* __restrict__ ei, const float* __restrict__ P,
    const float* __restrict__ W2, const float* __restrict__ b2,
    const float* __restrict__ W3, const float* __restrict__ b3,
    float* __restrict__ out, int E)
{
    __shared__ float sW2[32 * 32];
    __shared__ float sW3[64];
    __shared__ float sb2[32];
    __shared__ float sb3[2];
    for (int i = threadIdx.x; i < 1024; i += 256) sW2[i] = W2[i];
    if (threadIdx.x < 64) sW3[threadIdx.x] = W3[threadIdx.x];
    if (threadIdx.x < 32) sb2[threadIdx.x] = b2[threadIdx.x];
    if (threadIdx.x < 2)  sb3[threadIdx.x] = b3[threadIdx.x];
    __syncthreads();

    int e = blockIdx.x * 256 + threadIdx.x;
    if (e >= E) return;

    int s = ei[e];
    int d = ei[E + e];

    const float4* ps = (const float4*)(P + (size_t)s * 64);
    const float4* pd = (const float4*)(P + (size_t)d * 64 + 32);

    float h1[32];
#pragma unroll
    for (int j4 = 0; j4 < 8; ++j4) {
        float4 a = ps[j4];
        float4 b = pd[j4];
        h1[4*j4+0] = fmaxf(a.x + b.x, 0.0f);
        h1[4*j4+1] = fmaxf(a.y + b.y, 0.0f);
        h1[4*j4+2] = fmaxf(a.z + b.z, 0.0f);
        h1[4*j4+3] = fmaxf(a.w + b.w, 0.0f);
    }

    float acc[32];
#pragma unroll
    for (int j = 0; j < 32; ++j) acc[j] = sb2[j];
#pragma unroll
    for (int k = 0; k < 32; ++k) {
        float hk = h1[k];
#pragma unroll
        for (int j4 = 0; j4 < 8; ++j4) {
            float4 w = *(const float4*)&sW2[k * 32 + j4 * 4];
            acc[4*j4+0] += hk * w.x;
            acc[4*j4+1] += hk * w.y;
            acc[4*j4+2] += hk * w.z;
            acc[4*j4+3] += hk * w.w;
        }
    }

    float l0 = sb3[0], l1 = sb3[1];
#pragma unroll
    for (int k = 0; k < 32; ++k) {
        float h2k = fmaxf(acc[k], 0.0f);
        l0 += h2k * sW3[k * 2 + 0];
        l1 += h2k * sW3[k * 2 + 1];
    }

    // stable 2-class log_softmax
    float m = fmaxf(l0, l1);
    float z = __expf(l0 - m) + __expf(l1 - m);
    float lse = m + __logf(z);
    out[2 * (size_t)e + 0] = l0 - lse;
    out[2 * (size_t)e + 1] = l1 - lse;
}

extern "C" void kernel_launch(void* const* d_in, const int* in_sizes, int n_in,
                              void* d_out, int out_size, void* d_ws, size_t ws_size,
                              hipStream_t stream) {
    const float* X  = (const float*)d_in[0];
    const int*   ei = (const int*)d_in[1];
    const float* W1 = (const float*)d_in[2];
    const float* b1 = (const float*)d_in[3];
    const float* W2 = (const float*)d_in[4];
    const float* b2 = (const float*)d_in[5];
    const float* W3 = (const float*)d_in[6];
    const float* b3 = (const float*)d_in[7];
    float* out = (float*)d_out;

    int N = in_sizes[0] / D_NODE;   // 100000
    int E = in_sizes[1] / 2;        // 1600000

    float* P = (float*)d_ws;        // 100000 * 64 floats = 25.6 MB

    proj_kernel<<<(N + 255) / 256, 256, 0, stream>>>(X, W1, b1, P, N);
    edge_kernel<<<(E + 255) / 256, 256, 0, stream>>>(ei, P, W2, b2, W3, b3, out, E);
}